// Round 1
// baseline (4683.541 us; speedup 1.0000x reference)
//
#include <hip/hip_runtime.h>
#include <math.h>

// ---- weight buffer layout (floats) ----
#define WOFS1 0
#define BOFS1 80
#define WOFS2 96
#define BOFS2 608
#define WOFS3 640
#define BOFS3 1200
#define WOFS4 1216
#define BOFS4 1232
#define WTOT  1233

__device__ __forceinline__ float softplus_f(float x) {
  // log1p(exp(x)) stable form
  return fmaxf(x, 0.f) + log1pf(expf(-fabsf(x)));
}

struct PrepArgs {
  const float* wmu[4]; const float* wrho[4]; const float* epsw[4];
  const float* bmu[4]; const float* brho[4]; const float* epsb[4];
  float* out;
};

// 8 blocks: 0..3 = weight matrices, 4..7 = biases
__global__ void prep_kernel(PrepArgs a) {
  const int wsz[4] = {80, 512, 560, 16};
  const int wof[4] = {WOFS1, WOFS2, WOFS3, WOFS4};
  const int bsz[4] = {16, 32, 16, 1};
  const int bof[4] = {BOFS1, BOFS2, BOFS3, BOFS4};
  int b = blockIdx.x;
  if (b < 4) {
    const float* mu = a.wmu[b]; const float* rho = a.wrho[b]; const float* ep = a.epsw[b];
    float* o = a.out + wof[b];
    for (int i = threadIdx.x; i < wsz[b]; i += blockDim.x)
      o[i] = mu[i] + softplus_f(rho[i]) * ep[i];
  } else {
    int l = b - 4;
    const float* mu = a.bmu[l]; const float* rho = a.brho[l]; const float* ep = a.epsb[l];
    float* o = a.out + bof[l];
    for (int i = threadIdx.x; i < bsz[l]; i += blockDim.x)
      o[i] = mu[i] + softplus_f(rho[i]) * ep[i];
  }
}

__global__ void zero_kernel(int* __restrict__ p, int n) {
  int i = blockIdx.x * blockDim.x + threadIdx.x;
  if (i < n) p[i] = 0;
}

__global__ void count_kernel(const int* __restrict__ dst, int* __restrict__ deg, int E) {
  int e = blockIdx.x * blockDim.x + threadIdx.x;
  if (e < E) atomicAdd(&deg[dst[e]], 1);
}

// single-block exclusive scan over n entries; writes row_ptr[0..n] and cursor[0..n-1]
__global__ void scan_kernel(const int* __restrict__ deg, int* __restrict__ row_ptr,
                            int* __restrict__ cursor, int n) {
  __shared__ int wsum[16];
  __shared__ int woff[16];
  __shared__ int carry_s;
  __shared__ int total_s;
  int tid = threadIdx.x;
  int lane = tid & 63;
  int wid = tid >> 6;
  if (tid == 0) carry_s = 0;
  __syncthreads();
  for (int base = 0; base < n; base += 1024) {
    int i = base + tid;
    int v = (i < n) ? deg[i] : 0;
    int x = v;
#pragma unroll
    for (int off = 1; off < 64; off <<= 1) {
      int t = __shfl_up(x, off, 64);
      if (lane >= off) x += t;
    }
    if (lane == 63) wsum[wid] = x;
    __syncthreads();
    if (wid == 0) {
      int s = (lane < 16) ? wsum[lane] : 0;
#pragma unroll
      for (int off = 1; off < 16; off <<= 1) {
        int t = __shfl_up(s, off, 64);
        if (lane >= off) s += t;
      }
      if (lane < 16) woff[lane] = s - wsum[lane];  // exclusive wave offsets
      if (lane == 15) total_s = s;
    }
    __syncthreads();
    int incl = x + woff[wid];
    int carry = carry_s;
    if (i < n) {
      int e = carry + incl - v;
      row_ptr[i] = e;
      cursor[i] = e;
    }
    __syncthreads();
    if (tid == 0) carry_s += total_s;
    __syncthreads();
  }
  if (threadIdx.x == 0) row_ptr[n] = carry_s;
}

__global__ void fill_kernel(const int* __restrict__ src, const int* __restrict__ dst,
                            const float2* __restrict__ ea, int* __restrict__ cursor,
                            int* __restrict__ srt, float2* __restrict__ eas, int E) {
  int e = blockIdx.x * blockDim.x + threadIdx.x;
  if (e >= E) return;
  int d = dst[e];
  int pos = atomicAdd(&cursor[d], 1);
  srt[pos] = src[e];
  eas[pos] = ea[e];
}

// fused: per-node, loop over in-edges computing edge MLP inline, max in regs,
// then node MLP + sigmoid, write next x.
__global__ __launch_bounds__(256) void node_kernel(
    const float* __restrict__ xin, float* __restrict__ xout,
    const float* __restrict__ wg, const int* __restrict__ row,
    const int* __restrict__ srt, const float2* __restrict__ eas, int n) {
  __shared__ float w[WTOT];
  for (int i = threadIdx.x; i < WTOT; i += blockDim.x) w[i] = wg[i];
  __syncthreads();
  int nid = blockIdx.x * blockDim.x + threadIdx.x;
  if (nid >= n) return;
  int e0 = row[nid], e1 = row[nid + 1];
  float agg[32];
#pragma unroll
  for (int o = 0; o < 32; o++) agg[o] = 0.f;  // init 0 == where(isneginf,0) since relu>=0
  for (int e = e0; e < e1; e++) {
    int s = srt[e];
    float2 ea = eas[e];
    float in5[5];
    in5[0] = xin[3 * s];
    in5[1] = xin[3 * s + 1];
    in5[2] = xin[3 * s + 2];
    in5[3] = ea.x;
    in5[4] = ea.y;
    float m1[16];
#pragma unroll
    for (int o = 0; o < 16; o++) {
      float sa = w[BOFS1 + o];
#pragma unroll
      for (int k = 0; k < 5; k++) sa = fmaf(w[WOFS1 + o * 5 + k], in5[k], sa);
      m1[o] = fmaxf(sa, 0.f);
    }
#pragma unroll
    for (int o = 0; o < 32; o++) {
      float sa = w[BOFS2 + o];
#pragma unroll
      for (int k = 0; k < 16; k++) sa = fmaf(w[WOFS2 + o * 16 + k], m1[k], sa);
      agg[o] = fmaxf(agg[o], fmaxf(sa, 0.f));
    }
  }
  float x0 = xin[3 * nid], x1 = xin[3 * nid + 1], x2 = xin[3 * nid + 2];
  float h[16];
#pragma unroll
  for (int o = 0; o < 16; o++) {
    float sa = w[BOFS3 + o];
    sa = fmaf(w[WOFS3 + o * 35 + 0], x0, sa);
    sa = fmaf(w[WOFS3 + o * 35 + 1], x1, sa);
    sa = fmaf(w[WOFS3 + o * 35 + 2], x2, sa);
#pragma unroll
    for (int k = 0; k < 32; k++) sa = fmaf(w[WOFS3 + o * 35 + 3 + k], agg[k], sa);
    h[o] = fmaxf(sa, 0.f);
  }
  float z = w[BOFS4];
#pragma unroll
  for (int k = 0; k < 16; k++) z = fmaf(w[WOFS4 + k], h[k], z);
  float comb = 1.f / (1.f + expf(-z));
  xout[3 * nid] = x0;
  xout[3 * nid + 1] = x1;
  xout[3 * nid + 2] = comb;
}

extern "C" void kernel_launch(void* const* d_in, const int* in_sizes, int n_in,
                              void* d_out, int out_size, void* d_ws, size_t ws_size,
                              hipStream_t stream) {
  const float* x = (const float*)d_in[0];
  const float* ea = (const float*)d_in[1];
  const int* eidx = (const int*)d_in[2];
  const int N = in_sizes[0] / 3;
  const int E = in_sizes[1] / 2;
  const int* src = eidx;
  const int* dst = eidx + E;

  // ---- workspace carve-up ----
  char* p = (char*)d_ws;
  size_t off = 0;
  auto alloc = [&](size_t bytes) -> char* {
    char* r = p + off;
    off = (off + bytes + 255) & ~(size_t)255;
    return r;
  };
  float* wbuf = (float*)alloc((size_t)WTOT * 4);
  int* deg = (int*)alloc((size_t)N * 4);
  int* row = (int*)alloc(((size_t)N + 1) * 4);
  int* cursor = (int*)alloc((size_t)N * 4);
  int* srt = (int*)alloc((size_t)E * 4);
  float2* eas = (float2*)alloc((size_t)E * 8);
  float* bufA = (float*)alloc((size_t)N * 12);
  float* bufB = (float*)alloc((size_t)N * 12);
  (void)ws_size;

  PrepArgs pa;
  for (int l = 0; l < 4; l++) {
    pa.wmu[l] = (const float*)d_in[3 + 6 * l + 0];
    pa.wrho[l] = (const float*)d_in[3 + 6 * l + 1];
    pa.bmu[l] = (const float*)d_in[3 + 6 * l + 2];
    pa.brho[l] = (const float*)d_in[3 + 6 * l + 3];
    pa.epsw[l] = (const float*)d_in[3 + 6 * l + 4];
    pa.epsb[l] = (const float*)d_in[3 + 6 * l + 5];
  }
  pa.out = wbuf;

  const int TB = 256;
  zero_kernel<<<dim3((N + TB - 1) / TB), dim3(TB), 0, stream>>>(deg, N);
  prep_kernel<<<dim3(8), dim3(128), 0, stream>>>(pa);
  count_kernel<<<dim3((E + TB - 1) / TB), dim3(TB), 0, stream>>>(dst, deg, E);
  scan_kernel<<<dim3(1), dim3(1024), 0, stream>>>(deg, row, cursor, N);
  fill_kernel<<<dim3((E + TB - 1) / TB), dim3(TB), 0, stream>>>(
      src, dst, (const float2*)ea, cursor, srt, eas, E);

  float* outp = (float*)d_out;
  int nb = (N + TB - 1) / TB;
  node_kernel<<<dim3(nb), dim3(TB), 0, stream>>>(x, bufB, wbuf, row, srt, eas, N);
  node_kernel<<<dim3(nb), dim3(TB), 0, stream>>>(bufB, bufA, wbuf, row, srt, eas, N);
  node_kernel<<<dim3(nb), dim3(TB), 0, stream>>>(bufA, outp, wbuf, row, srt, eas, N);
}

// Round 2
// 3880.806 us; speedup vs baseline: 1.2068x; 1.2068x over previous
//
#include <hip/hip_runtime.h>
#include <math.h>

// ---- weight buffer layout (floats) ----
#define WOFS1 0
#define BOFS1 80
#define WOFS2 96
#define BOFS2 608
#define WOFS3 640
#define BOFS3 1200
#define WOFS4 1216
#define BOFS4 1232
#define WTOT  1233

#define NB 65536  // degree histogram bins (capped)

__device__ __forceinline__ float softplus_f(float x) {
  return fmaxf(x, 0.f) + log1pf(expf(-fabsf(x)));
}

struct PrepArgs {
  const float* wmu[4]; const float* wrho[4]; const float* epsw[4];
  const float* bmu[4]; const float* brho[4]; const float* epsb[4];
  float* out;
};

__global__ void prep_kernel(PrepArgs a) {
  const int wsz[4] = {80, 512, 560, 16};
  const int wof[4] = {WOFS1, WOFS2, WOFS3, WOFS4};
  const int bsz[4] = {16, 32, 16, 1};
  const int bof[4] = {BOFS1, BOFS2, BOFS3, BOFS4};
  int b = blockIdx.x;
  if (b < 4) {
    const float* mu = a.wmu[b]; const float* rho = a.wrho[b]; const float* ep = a.epsw[b];
    float* o = a.out + wof[b];
    for (int i = threadIdx.x; i < wsz[b]; i += blockDim.x)
      o[i] = mu[i] + softplus_f(rho[i]) * ep[i];
  } else {
    int l = b - 4;
    const float* mu = a.bmu[l]; const float* rho = a.brho[l]; const float* ep = a.epsb[l];
    float* o = a.out + bof[l];
    for (int i = threadIdx.x; i < bsz[l]; i += blockDim.x)
      o[i] = mu[i] + softplus_f(rho[i]) * ep[i];
  }
}

__global__ void zero_kernel(int* __restrict__ p, int n) {
  int i = blockIdx.x * blockDim.x + threadIdx.x;
  if (i < n) p[i] = 0;
}

__global__ void count_kernel(const int* __restrict__ dst, int* __restrict__ deg, int E) {
  int e = blockIdx.x * blockDim.x + threadIdx.x;
  if (e < E) atomicAdd(&deg[dst[e]], 1);
}

// descending-degree key
__device__ __forceinline__ int dkey(int d) { return (NB - 1) - min(d, NB - 1); }

__global__ void hist_kernel(const int* __restrict__ deg, int* __restrict__ hist, int n) {
  int i = blockIdx.x * blockDim.x + threadIdx.x;
  if (i < n) atomicAdd(&hist[dkey(deg[i])], 1);
}

// single-block exclusive scan; writes row_ptr[0..n] and cursor[0..n-1]
__global__ void scan_kernel(const int* __restrict__ deg, int* __restrict__ row_ptr,
                            int* __restrict__ cursor, int n) {
  __shared__ int wsum[16];
  __shared__ int woff[16];
  __shared__ int carry_s;
  __shared__ int total_s;
  int tid = threadIdx.x;
  int lane = tid & 63;
  int wid = tid >> 6;
  if (tid == 0) carry_s = 0;
  __syncthreads();
  for (int base = 0; base < n; base += 1024) {
    int i = base + tid;
    int v = (i < n) ? deg[i] : 0;
    int x = v;
#pragma unroll
    for (int off = 1; off < 64; off <<= 1) {
      int t = __shfl_up(x, off, 64);
      if (lane >= off) x += t;
    }
    if (lane == 63) wsum[wid] = x;
    __syncthreads();
    if (wid == 0) {
      int s = (lane < 16) ? wsum[lane] : 0;
#pragma unroll
      for (int off = 1; off < 16; off <<= 1) {
        int t = __shfl_up(s, off, 64);
        if (lane >= off) s += t;
      }
      if (lane < 16) woff[lane] = s - wsum[lane];
      if (lane == 15) total_s = s;
    }
    __syncthreads();
    int incl = x + woff[wid];
    int carry = carry_s;
    if (i < n) {
      int e = carry + incl - v;
      row_ptr[i] = e;
      cursor[i] = e;
    }
    __syncthreads();
    if (tid == 0) carry_s += total_s;
    __syncthreads();
  }
  if (threadIdx.x == 0) row_ptr[n] = carry_s;
}

__global__ void rank_kernel(const int* __restrict__ deg, int* __restrict__ histCur,
                            int* __restrict__ srank, int* __restrict__ order, int n) {
  int i = blockIdx.x * blockDim.x + threadIdx.x;
  if (i >= n) return;
  int pos = atomicAdd(&histCur[dkey(deg[i])], 1);
  srank[i] = pos;
  order[pos] = i;
}

__global__ void harr_kernel(const int* __restrict__ deg, const int* __restrict__ order,
                            int* __restrict__ Harr, int n, int G) {
  int g = blockIdx.x * blockDim.x + threadIdx.x;
  if (g >= G) return;
  int s = g * 64;
  int e = min(s + 64, n);
  int m = 0;
  for (int i = s; i < e; i++) m = max(m, deg[order[i]]);
  Harr[g] = m;
}

__global__ void fill_kernel(const int* __restrict__ src, const int* __restrict__ dst,
                            const float2* __restrict__ ea, int* __restrict__ cursor,
                            const int* __restrict__ row, const int* __restrict__ srank,
                            const int* __restrict__ tileOff, int4* __restrict__ trans,
                            int capRows, int E) {
  int e = blockIdx.x * blockDim.x + threadIdx.x;
  if (e >= E) return;
  int d = dst[e];
  int pos = atomicAdd(&cursor[d], 1);
  int p = pos - row[d];
  int r = srank[d];
  int rowIdx = tileOff[r >> 6] + p;
  if (rowIdx >= capRows) return;  // overflow guard (degrades to wrong, not crash)
  float2 a = ea[e];
  trans[(rowIdx << 6) | (r & 63)] = make_int4(src[e], __float_as_int(a.x),
                                              __float_as_int(a.y), 0);
}

__global__ void xprep_kernel(const float* __restrict__ x, float4* __restrict__ x4, int n) {
  int i = blockIdx.x * blockDim.x + threadIdx.x;
  if (i < n) x4[i] = make_float4(x[3 * i], x[3 * i + 1], x[3 * i + 2], 0.f);
}

// fused: coalesced transposed-ELL edge loop (edge MLP + max in regs) + node MLP
__global__ __launch_bounds__(256) void node_kernel(
    const float4* __restrict__ x4in, float4* __restrict__ x4out,
    float* __restrict__ outFinal, const float* __restrict__ wg,
    const int* __restrict__ deg, const int* __restrict__ order,
    const int* __restrict__ tileOff, const int4* __restrict__ trans, int n) {
  __shared__ float w[WTOT];
  for (int i = threadIdx.x; i < WTOT; i += blockDim.x) w[i] = wg[i];
  __syncthreads();
  int tid = blockIdx.x * blockDim.x + threadIdx.x;
  if (tid >= n) return;
  int nid = order[tid];
  int dn = deg[nid];
  int g = tid >> 6;
  int lane = tid & 63;
  int row0 = tileOff[g];
  int H = tileOff[g + 1] - row0;
  int base = (row0 << 6) | lane;

  float agg[32];
#pragma unroll
  for (int o = 0; o < 32; o++) agg[o] = 0.f;  // == where(isneginf,0) since relu>=0

  for (int i = 0; i < H; i++) {
    if (i < dn) {
      int4 rec = trans[base + (i << 6)];
      float4 xs = x4in[rec.x];
      float in5[5];
      in5[0] = xs.x; in5[1] = xs.y; in5[2] = xs.z;
      in5[3] = __int_as_float(rec.y); in5[4] = __int_as_float(rec.z);
      float m1[16];
#pragma unroll
      for (int o = 0; o < 16; o++) {
        float sa = w[BOFS1 + o];
#pragma unroll
        for (int k = 0; k < 5; k++) sa = fmaf(w[WOFS1 + o * 5 + k], in5[k], sa);
        m1[o] = fmaxf(sa, 0.f);
      }
#pragma unroll
      for (int o = 0; o < 32; o++) {
        float sa = w[BOFS2 + o];
#pragma unroll
        for (int k = 0; k < 16; k++) sa = fmaf(w[WOFS2 + o * 16 + k], m1[k], sa);
        agg[o] = fmaxf(agg[o], fmaxf(sa, 0.f));
      }
    }
  }

  float4 xs = x4in[nid];
  float h[16];
#pragma unroll
  for (int o = 0; o < 16; o++) {
    float sa = w[BOFS3 + o];
    sa = fmaf(w[WOFS3 + o * 35 + 0], xs.x, sa);
    sa = fmaf(w[WOFS3 + o * 35 + 1], xs.y, sa);
    sa = fmaf(w[WOFS3 + o * 35 + 2], xs.z, sa);
#pragma unroll
    for (int k = 0; k < 32; k++) sa = fmaf(w[WOFS3 + o * 35 + 3 + k], agg[k], sa);
    h[o] = fmaxf(sa, 0.f);
  }
  float z = w[BOFS4];
#pragma unroll
  for (int k = 0; k < 16; k++) z = fmaf(w[WOFS4 + k], h[k], z);
  float comb = 1.f / (1.f + expf(-z));
  x4out[nid] = make_float4(xs.x, xs.y, comb, 0.f);
  if (outFinal) {
    outFinal[3 * nid] = xs.x;
    outFinal[3 * nid + 1] = xs.y;
    outFinal[3 * nid + 2] = comb;
  }
}

extern "C" void kernel_launch(void* const* d_in, const int* in_sizes, int n_in,
                              void* d_out, int out_size, void* d_ws, size_t ws_size,
                              hipStream_t stream) {
  const float* x = (const float*)d_in[0];
  const float* ea = (const float*)d_in[1];
  const int* eidx = (const int*)d_in[2];
  const int N = in_sizes[0] / 3;
  const int E = in_sizes[1] / 2;
  const int G = (N + 63) / 64;
  const int* src = eidx;
  const int* dst = eidx + E;

  // ---- workspace carve-up ----
  char* p = (char*)d_ws;
  size_t off = 0;
  auto alloc = [&](size_t bytes) -> char* {
    char* r = p + off;
    off = (off + bytes + 255) & ~(size_t)255;
    return r;
  };
  float* wbuf = (float*)alloc((size_t)WTOT * 4);
  int* deg = (int*)alloc((size_t)N * 4);
  int* row = (int*)alloc(((size_t)N + 1) * 4);
  int* cursor = (int*)alloc((size_t)N * 4);
  int* hist = (int*)alloc((size_t)NB * 4);
  int* histOff = (int*)alloc(((size_t)NB + 1) * 4);
  int* histCur = (int*)alloc((size_t)NB * 4);
  int* srank = (int*)alloc((size_t)N * 4);
  int* order = (int*)alloc((size_t)N * 4);
  int* Harr = (int*)alloc((size_t)G * 4);
  int* tileOff = (int*)alloc(((size_t)G + 1) * 4);
  int* dummyCur = (int*)alloc((size_t)G * 4);
  float4* x4a = (float4*)alloc((size_t)N * 16);
  float4* x4b = (float4*)alloc((size_t)N * 16);
  // trans takes the remaining workspace (cap in 64-record rows)
  size_t remain = (ws_size > off) ? (ws_size - off) : 0;
  int capRows = (int)(remain / (64 * 16));
  int4* trans = (int4*)(p + off);

  PrepArgs pa;
  for (int l = 0; l < 4; l++) {
    pa.wmu[l] = (const float*)d_in[3 + 6 * l + 0];
    pa.wrho[l] = (const float*)d_in[3 + 6 * l + 1];
    pa.bmu[l] = (const float*)d_in[3 + 6 * l + 2];
    pa.brho[l] = (const float*)d_in[3 + 6 * l + 3];
    pa.epsw[l] = (const float*)d_in[3 + 6 * l + 4];
    pa.epsb[l] = (const float*)d_in[3 + 6 * l + 5];
  }
  pa.out = wbuf;

  const int TB = 256;
  auto blocks = [&](int n) { return dim3((n + TB - 1) / TB); };

  zero_kernel<<<blocks(N), dim3(TB), 0, stream>>>(deg, N);
  zero_kernel<<<blocks(NB), dim3(TB), 0, stream>>>(hist, NB);
  prep_kernel<<<dim3(8), dim3(128), 0, stream>>>(pa);
  count_kernel<<<blocks(E), dim3(TB), 0, stream>>>(dst, deg, E);
  hist_kernel<<<blocks(N), dim3(TB), 0, stream>>>(deg, hist, N);
  scan_kernel<<<dim3(1), dim3(1024), 0, stream>>>(deg, row, cursor, N);
  scan_kernel<<<dim3(1), dim3(1024), 0, stream>>>(hist, histOff, histCur, NB);
  rank_kernel<<<blocks(N), dim3(TB), 0, stream>>>(deg, histCur, srank, order, N);
  harr_kernel<<<blocks(G), dim3(TB), 0, stream>>>(deg, order, Harr, N, G);
  scan_kernel<<<dim3(1), dim3(1024), 0, stream>>>(Harr, tileOff, dummyCur, G);
  fill_kernel<<<blocks(E), dim3(TB), 0, stream>>>(src, dst, (const float2*)ea, cursor,
                                                  row, srank, tileOff, trans, capRows, E);
  xprep_kernel<<<blocks(N), dim3(TB), 0, stream>>>(x, x4a, N);

  float* outp = (float*)d_out;
  node_kernel<<<blocks(N), dim3(TB), 0, stream>>>(x4a, x4b, nullptr, wbuf, deg, order,
                                                  tileOff, trans, N);
  node_kernel<<<blocks(N), dim3(TB), 0, stream>>>(x4b, x4a, nullptr, wbuf, deg, order,
                                                  tileOff, trans, N);
  node_kernel<<<blocks(N), dim3(TB), 0, stream>>>(x4a, x4b, outp, wbuf, deg, order,
                                                  tileOff, trans, N);
}

// Round 3
// 1374.483 us; speedup vs baseline: 3.4075x; 2.8235x over previous
//
#include <hip/hip_runtime.h>
#include <math.h>

// ---- weight buffer layout (floats) ----
// W1[16][5]@0  b1@80 | W2[32][16]@96  b2@608 | W3[16][35]@640 b3@1200 | W4[16]@1216 b4@1232
#define WTOT   1233
#define EW_TOT 640   // layer1+layer2 block (offsets 0..639)
#define NW_TOT 593   // layer3+layer4 block (global offset 640..1232)

__device__ __forceinline__ float softplus_f(float x) {
  return fmaxf(x, 0.f) + log1pf(expf(-fabsf(x)));
}

struct PrepArgs {
  const float* wmu[4]; const float* wrho[4]; const float* epsw[4];
  const float* bmu[4]; const float* brho[4]; const float* epsb[4];
  float* out;
};

__global__ void prep_kernel(PrepArgs a) {
  const int wsz[4] = {80, 512, 560, 16};
  const int wof[4] = {0, 96, 640, 1216};
  const int bsz[4] = {16, 32, 16, 1};
  const int bof[4] = {80, 608, 1200, 1232};
  int b = blockIdx.x;
  if (b < 4) {
    const float* mu = a.wmu[b]; const float* rho = a.wrho[b]; const float* ep = a.epsw[b];
    float* o = a.out + wof[b];
    for (int i = threadIdx.x; i < wsz[b]; i += blockDim.x)
      o[i] = mu[i] + softplus_f(rho[i]) * ep[i];
  } else {
    int l = b - 4;
    const float* mu = a.bmu[l]; const float* rho = a.brho[l]; const float* ep = a.epsb[l];
    float* o = a.out + bof[l];
    for (int i = threadIdx.x; i < bsz[l]; i += blockDim.x)
      o[i] = mu[i] + softplus_f(rho[i]) * ep[i];
  }
}

__global__ void zero_kernel(int* __restrict__ p, int n) {
  int i = blockIdx.x * blockDim.x + threadIdx.x;
  if (i < n) p[i] = 0;
}

__global__ void zero4_kernel(uint4* __restrict__ p, int n4) {
  int i = blockIdx.x * blockDim.x + threadIdx.x;
  if (i < n4) p[i] = make_uint4(0u, 0u, 0u, 0u);
}

__global__ void count_kernel(const int* __restrict__ dst, int* __restrict__ deg, int E) {
  int e = blockIdx.x * blockDim.x + threadIdx.x;
  if (e < E) atomicAdd(&deg[dst[e]], 1);
}

// single-block exclusive scan; writes row_ptr[0..n] and cursor[0..n-1]
__global__ void scan_kernel(const int* __restrict__ deg, int* __restrict__ row_ptr,
                            int* __restrict__ cursor, int n) {
  __shared__ int wsum[16];
  __shared__ int woff[16];
  __shared__ int carry_s;
  __shared__ int total_s;
  int tid = threadIdx.x;
  int lane = tid & 63;
  int wid = tid >> 6;
  if (tid == 0) carry_s = 0;
  __syncthreads();
  for (int base = 0; base < n; base += 1024) {
    int i = base + tid;
    int v = (i < n) ? deg[i] : 0;
    int x = v;
#pragma unroll
    for (int off = 1; off < 64; off <<= 1) {
      int t = __shfl_up(x, off, 64);
      if (lane >= off) x += t;
    }
    if (lane == 63) wsum[wid] = x;
    __syncthreads();
    if (wid == 0) {
      int s = (lane < 16) ? wsum[lane] : 0;
#pragma unroll
      for (int off = 1; off < 16; off <<= 1) {
        int t = __shfl_up(s, off, 64);
        if (lane >= off) s += t;
      }
      if (lane < 16) woff[lane] = s - wsum[lane];
      if (lane == 15) total_s = s;
    }
    __syncthreads();
    int incl = x + woff[wid];
    int carry = carry_s;
    if (i < n) {
      int e = carry + incl - v;
      row_ptr[i] = e;
      cursor[i] = e;
    }
    __syncthreads();
    if (tid == 0) carry_s += total_s;
    __syncthreads();
  }
  if (threadIdx.x == 0) row_ptr[n] = carry_s;
}

__global__ void fill_kernel(const int* __restrict__ src, const int* __restrict__ dst,
                            const float2* __restrict__ ea, int* __restrict__ cursor,
                            int* __restrict__ srt, float2* __restrict__ eas,
                            int* __restrict__ dsts, int E) {
  int e = blockIdx.x * blockDim.x + threadIdx.x;
  if (e >= E) return;
  int d = dst[e];
  int pos = atomicAdd(&cursor[d], 1);
  srt[pos] = src[e];
  eas[pos] = ea[e];
  dsts[pos] = d;
}

__global__ void xprep_kernel(const float* __restrict__ x, float4* __restrict__ x4, int n) {
  int i = blockIdx.x * blockDim.x + threadIdx.x;
  if (i < n) x4[i] = make_float4(x[3 * i], x[3 * i + 1], x[3 * i + 2], 0.f);
}

// edge-parallel: one thread per (dst-sorted) edge. Edge MLP in regs, wave-level
// segmented max over contiguous equal-dst runs, run heads do 32 atomicMax.
__global__ __launch_bounds__(256) void edge_kernel(
    const float4* __restrict__ x4, const int* __restrict__ srt,
    const float2* __restrict__ eas, const int* __restrict__ dsts,
    unsigned int* __restrict__ agg, const float* __restrict__ wg, int E) {
  __shared__ float w[EW_TOT];
  for (int i = threadIdx.x; i < EW_TOT; i += blockDim.x) w[i] = wg[i];
  __syncthreads();
  int e = blockIdx.x * blockDim.x + threadIdx.x;
  bool valid = e < E;
  int d = -1;
  float m[32];
  if (valid) {
    d = dsts[e];
    int s = srt[e];
    float2 ea = eas[e];
    float4 xs = x4[s];
    float in5[5];
    in5[0] = xs.x; in5[1] = xs.y; in5[2] = xs.z; in5[3] = ea.x; in5[4] = ea.y;
    float m1[16];
#pragma unroll
    for (int o = 0; o < 16; o++) {
      float sa = w[80 + o];
#pragma unroll
      for (int k = 0; k < 5; k++) sa = fmaf(w[o * 5 + k], in5[k], sa);
      m1[o] = fmaxf(sa, 0.f);
    }
#pragma unroll
    for (int o = 0; o < 32; o++) {
      float sa = w[608 + o];
#pragma unroll
      for (int k = 0; k < 16; k++) sa = fmaf(w[96 + o * 16 + k], m1[k], sa);
      m[o] = fmaxf(sa, 0.f);
    }
  } else {
#pragma unroll
    for (int o = 0; o < 32; o++) m[o] = 0.f;
  }
  int lane = threadIdx.x & 63;
  // segmented max-reduce to run head (dst runs are contiguous)
#pragma unroll
  for (int off = 1; off < 64; off <<= 1) {
    int d2 = __shfl_down(d, off, 64);
    bool take = (lane + off < 64) && (d2 == d);
#pragma unroll
    for (int o = 0; o < 32; o++) {
      float v2 = __shfl_down(m[o], off, 64);
      if (take) m[o] = fmaxf(m[o], v2);
    }
  }
  int dprev = __shfl_up(d, 1, 64);
  bool head = valid && (lane == 0 || dprev != d);
  if (head) {
    unsigned int* a = agg + (size_t)d * 32;
#pragma unroll
    for (int o = 0; o < 32; o++) atomicMax(a + o, __float_as_uint(m[o]));
  }
}

// node-parallel: read agg (uint bits of non-negative floats), re-zero it for the
// next iteration, apply node MLP + sigmoid, write next x (and final out).
__global__ __launch_bounds__(256) void node_kernel(
    const float4* __restrict__ x4in, float4* __restrict__ x4out,
    float* __restrict__ outFinal, unsigned int* __restrict__ agg,
    const float* __restrict__ wg, int n) {
  __shared__ float w[NW_TOT];
  for (int i = threadIdx.x; i < NW_TOT; i += blockDim.x) w[i] = wg[640 + i];
  __syncthreads();
  int nid = blockIdx.x * blockDim.x + threadIdx.x;
  if (nid >= n) return;
  unsigned int* a = agg + (size_t)nid * 32;
  float av[32];
#pragma unroll
  for (int o = 0; o < 32; o += 4) {
    uint4 u = *(const uint4*)(a + o);
    av[o] = __uint_as_float(u.x);
    av[o + 1] = __uint_as_float(u.y);
    av[o + 2] = __uint_as_float(u.z);
    av[o + 3] = __uint_as_float(u.w);
    *(uint4*)(a + o) = make_uint4(0u, 0u, 0u, 0u);
  }
  float4 xs = x4in[nid];
  float h[16];
#pragma unroll
  for (int o = 0; o < 16; o++) {
    float sa = w[560 + o];  // b3 (local)
    sa = fmaf(w[o * 35 + 0], xs.x, sa);
    sa = fmaf(w[o * 35 + 1], xs.y, sa);
    sa = fmaf(w[o * 35 + 2], xs.z, sa);
#pragma unroll
    for (int k = 0; k < 32; k++) sa = fmaf(w[o * 35 + 3 + k], av[k], sa);
    h[o] = fmaxf(sa, 0.f);
  }
  float z = w[592];  // b4 (local)
#pragma unroll
  for (int k = 0; k < 16; k++) z = fmaf(w[576 + k], h[k], z);
  float comb = 1.f / (1.f + expf(-z));
  x4out[nid] = make_float4(xs.x, xs.y, comb, 0.f);
  if (outFinal) {
    outFinal[3 * nid] = xs.x;
    outFinal[3 * nid + 1] = xs.y;
    outFinal[3 * nid + 2] = comb;
  }
}

extern "C" void kernel_launch(void* const* d_in, const int* in_sizes, int n_in,
                              void* d_out, int out_size, void* d_ws, size_t ws_size,
                              hipStream_t stream) {
  const float* x = (const float*)d_in[0];
  const float* ea = (const float*)d_in[1];
  const int* eidx = (const int*)d_in[2];
  const int N = in_sizes[0] / 3;
  const int E = in_sizes[1] / 2;
  const int* src = eidx;
  const int* dst = eidx + E;

  // ---- workspace carve-up ----
  char* p = (char*)d_ws;
  size_t off = 0;
  auto alloc = [&](size_t bytes) -> char* {
    char* r = p + off;
    off = (off + bytes + 255) & ~(size_t)255;
    return r;
  };
  float* wbuf = (float*)alloc((size_t)WTOT * 4);
  int* deg = (int*)alloc((size_t)N * 4);
  int* row = (int*)alloc(((size_t)N + 1) * 4);
  int* cursor = (int*)alloc((size_t)N * 4);
  int* srt = (int*)alloc((size_t)E * 4);
  float2* eas = (float2*)alloc((size_t)E * 8);
  int* dsts = (int*)alloc((size_t)E * 4);
  unsigned int* agg = (unsigned int*)alloc((size_t)N * 32 * 4);
  float4* x4a = (float4*)alloc((size_t)N * 16);
  float4* x4b = (float4*)alloc((size_t)N * 16);
  (void)ws_size;

  PrepArgs pa;
  for (int l = 0; l < 4; l++) {
    pa.wmu[l] = (const float*)d_in[3 + 6 * l + 0];
    pa.wrho[l] = (const float*)d_in[3 + 6 * l + 1];
    pa.bmu[l] = (const float*)d_in[3 + 6 * l + 2];
    pa.brho[l] = (const float*)d_in[3 + 6 * l + 3];
    pa.epsw[l] = (const float*)d_in[3 + 6 * l + 4];
    pa.epsb[l] = (const float*)d_in[3 + 6 * l + 5];
  }
  pa.out = wbuf;

  const int TB = 256;
  auto blocks = [&](int n) { return dim3((n + TB - 1) / TB); };

  zero_kernel<<<blocks(N), dim3(TB), 0, stream>>>(deg, N);
  prep_kernel<<<dim3(8), dim3(128), 0, stream>>>(pa);
  count_kernel<<<blocks(E), dim3(TB), 0, stream>>>(dst, deg, E);
  scan_kernel<<<dim3(1), dim3(1024), 0, stream>>>(deg, row, cursor, N);
  fill_kernel<<<blocks(E), dim3(TB), 0, stream>>>(src, dst, (const float2*)ea, cursor,
                                                  srt, eas, dsts, E);
  xprep_kernel<<<blocks(N), dim3(TB), 0, stream>>>(x, x4a, N);
  int n4 = N * 8;  // N*32 uints as uint4
  zero4_kernel<<<blocks(n4), dim3(TB), 0, stream>>>((uint4*)agg, n4);

  float* outp = (float*)d_out;
  // iter 1
  edge_kernel<<<blocks(E), dim3(TB), 0, stream>>>(x4a, srt, eas, dsts, agg, wbuf, E);
  node_kernel<<<blocks(N), dim3(TB), 0, stream>>>(x4a, x4b, nullptr, agg, wbuf, N);
  // iter 2
  edge_kernel<<<blocks(E), dim3(TB), 0, stream>>>(x4b, srt, eas, dsts, agg, wbuf, E);
  node_kernel<<<blocks(N), dim3(TB), 0, stream>>>(x4b, x4a, nullptr, agg, wbuf, N);
  // iter 3
  edge_kernel<<<blocks(E), dim3(TB), 0, stream>>>(x4a, srt, eas, dsts, agg, wbuf, E);
  node_kernel<<<blocks(N), dim3(TB), 0, stream>>>(x4a, x4b, outp, agg, wbuf, N);
}

// Round 5
// 1350.989 us; speedup vs baseline: 3.4668x; 1.0174x over previous
//
#include <hip/hip_runtime.h>
#include <math.h>

// ---- weight buffer layout (floats) ----
// W1[16][5]@0  b1@80 | W2[32][16]@96  b2@608 | W3[16][35]@640 b3@1200 | W4[16]@1216 b4@1232
#define WTOT 1233

typedef __fp16 half2v __attribute__((ext_vector_type(2)));

__device__ __forceinline__ float softplus_f(float x) {
  return fmaxf(x, 0.f) + log1pf(expf(-fabsf(x)));
}

struct PrepArgs {
  const float* wmu[4]; const float* wrho[4]; const float* epsw[4];
  const float* bmu[4]; const float* brho[4]; const float* epsb[4];
  float* out;
};

__global__ void prep_kernel(PrepArgs a) {
  const int wsz[4] = {80, 512, 560, 16};
  const int wof[4] = {0, 96, 640, 1216};
  const int bsz[4] = {16, 32, 16, 1};
  const int bof[4] = {80, 608, 1200, 1232};
  int b = blockIdx.x;
  if (b < 4) {
    const float* mu = a.wmu[b]; const float* rho = a.wrho[b]; const float* ep = a.epsw[b];
    float* o = a.out + wof[b];
    for (int i = threadIdx.x; i < wsz[b]; i += blockDim.x)
      o[i] = mu[i] + softplus_f(rho[i]) * ep[i];
  } else {
    int l = b - 4;
    const float* mu = a.bmu[l]; const float* rho = a.brho[l]; const float* ep = a.epsb[l];
    float* o = a.out + bof[l];
    for (int i = threadIdx.x; i < bsz[l]; i += blockDim.x)
      o[i] = mu[i] + softplus_f(rho[i]) * ep[i];
  }
}

__global__ void zero_kernel(int* __restrict__ p, int n) {
  int i = blockIdx.x * blockDim.x + threadIdx.x;
  if (i < n) p[i] = 0;
}

__global__ void zero4_kernel(uint4* __restrict__ p, int n4) {
  int i = blockIdx.x * blockDim.x + threadIdx.x;
  if (i < n4) p[i] = make_uint4(0u, 0u, 0u, 0u);
}

__global__ void count_kernel(const int* __restrict__ dst, int* __restrict__ deg, int E) {
  int e = blockIdx.x * blockDim.x + threadIdx.x;
  if (e < E) atomicAdd(&deg[dst[e]], 1);
}

// single-block exclusive scan; writes row_ptr[0..n] and cursor[0..n-1]
__global__ void scan_kernel(const int* __restrict__ deg, int* __restrict__ row_ptr,
                            int* __restrict__ cursor, int n) {
  __shared__ int wsum[16];
  __shared__ int woff[16];
  __shared__ int carry_s;
  __shared__ int total_s;
  int tid = threadIdx.x;
  int lane = tid & 63;
  int wid = tid >> 6;
  if (tid == 0) carry_s = 0;
  __syncthreads();
  for (int base = 0; base < n; base += 1024) {
    int i = base + tid;
    int v = (i < n) ? deg[i] : 0;
    int x = v;
#pragma unroll
    for (int off = 1; off < 64; off <<= 1) {
      int t = __shfl_up(x, off, 64);
      if (lane >= off) x += t;
    }
    if (lane == 63) wsum[wid] = x;
    __syncthreads();
    if (wid == 0) {
      int s = (lane < 16) ? wsum[lane] : 0;
#pragma unroll
      for (int off = 1; off < 16; off <<= 1) {
        int t = __shfl_up(s, off, 64);
        if (lane >= off) s += t;
      }
      if (lane < 16) woff[lane] = s - wsum[lane];
      if (lane == 15) total_s = s;
    }
    __syncthreads();
    int incl = x + woff[wid];
    int carry = carry_s;
    if (i < n) {
      int e = carry + incl - v;
      row_ptr[i] = e;
      cursor[i] = e;
    }
    __syncthreads();
    if (tid == 0) carry_s += total_s;
    __syncthreads();
  }
  if (threadIdx.x == 0) row_ptr[n] = carry_s;
}

// write packed edge records sorted by dst: (src, ea.x, ea.y, dst)
__global__ void fill_kernel(const int* __restrict__ src, const int* __restrict__ dst,
                            const float2* __restrict__ ea, int* __restrict__ cursor,
                            int4* __restrict__ erec, int E) {
  int e = blockIdx.x * blockDim.x + threadIdx.x;
  if (e >= E) return;
  int d = dst[e];
  int pos = atomicAdd(&cursor[d], 1);
  float2 a = ea[e];
  erec[pos] = make_int4(src[e], __float_as_int(a.x), __float_as_int(a.y), d);
}

__global__ void xprep_kernel(const float* __restrict__ x, float4* __restrict__ x4, int n) {
  int i = blockIdx.x * blockDim.x + threadIdx.x;
  if (i < n) x4[i] = make_float4(x[3 * i], x[3 * i + 1], x[3 * i + 2], 0.f);
}

// edge-parallel: one thread per (dst-sorted) edge. Edge MLP in regs with weights
// from global (scalar-loaded, wave-uniform), fp16-packed wave-level segmented max,
// run heads do 32 atomicMax.
__global__ __launch_bounds__(256) void edge_kernel(
    const float4* __restrict__ x4, const int4* __restrict__ erec,
    unsigned int* __restrict__ agg, const float* __restrict__ wg, int E) {
  int e = blockIdx.x * blockDim.x + threadIdx.x;
  bool valid = e < E;
  int d = -1;
  unsigned int pk[16];
#pragma unroll
  for (int i = 0; i < 16; i++) pk[i] = 0u;
  if (valid) {
    int4 rec = erec[e];
    d = rec.w;
    float4 xs = x4[rec.x];
    float in5[5];
    in5[0] = xs.x; in5[1] = xs.y; in5[2] = xs.z;
    in5[3] = __int_as_float(rec.y); in5[4] = __int_as_float(rec.z);
    float m1[16];
#pragma unroll
    for (int o = 0; o < 16; o++) {
      float sa = wg[80 + o];
#pragma unroll
      for (int k = 0; k < 5; k++) sa = fmaf(wg[o * 5 + k], in5[k], sa);
      m1[o] = fmaxf(sa, 0.f);
    }
#pragma unroll
    for (int o2 = 0; o2 < 16; o2++) {
      float sa = wg[608 + 2 * o2];
      float sb = wg[608 + 2 * o2 + 1];
#pragma unroll
      for (int k = 0; k < 16; k++) {
        sa = fmaf(wg[96 + (2 * o2) * 16 + k], m1[k], sa);
        sb = fmaf(wg[96 + (2 * o2 + 1) * 16 + k], m1[k], sb);
      }
      half2v h = __builtin_amdgcn_cvt_pkrtz(fmaxf(sa, 0.f), fmaxf(sb, 0.f));
      pk[o2] = __builtin_bit_cast(unsigned int, h);
    }
  }
  int lane = threadIdx.x & 63;
  // segmented max-reduce to run head (dst runs are contiguous; values >= 0 so
  // masking the incoming value to +0.0 is a no-op for max)
#pragma unroll
  for (int off = 1; off < 64; off <<= 1) {
    int d2 = __shfl_down(d, off, 64);
    unsigned int msk = ((lane + off < 64) && (d2 == d)) ? 0xFFFFFFFFu : 0u;
#pragma unroll
    for (int i = 0; i < 16; i++) {
      unsigned int v2 = __shfl_down(pk[i], off, 64) & msk;
      half2v a = __builtin_bit_cast(half2v, pk[i]);
      half2v b = __builtin_bit_cast(half2v, v2);
      half2v r = __builtin_elementwise_max(a, b);
      pk[i] = __builtin_bit_cast(unsigned int, r);
    }
  }
  int dprev = __shfl_up(d, 1, 64);
  bool head = valid && (lane == 0 || dprev != d);
  if (head) {
    unsigned int* a = agg + (size_t)d * 32;
#pragma unroll
    for (int i = 0; i < 16; i++) {
      half2v h = __builtin_bit_cast(half2v, pk[i]);
      atomicMax(a + 2 * i, __float_as_uint((float)h.x));
      atomicMax(a + 2 * i + 1, __float_as_uint((float)h.y));
    }
  }
}

// node-parallel: read agg (uint bits of non-negative floats), re-zero it for the
// next iteration, apply node MLP + sigmoid, write next x (and final out).
__global__ __launch_bounds__(256) void node_kernel(
    const float4* __restrict__ x4in, float4* __restrict__ x4out,
    float* __restrict__ outFinal, unsigned int* __restrict__ agg,
    const float* __restrict__ wg, int n) {
  int nid = blockIdx.x * blockDim.x + threadIdx.x;
  if (nid >= n) return;
  unsigned int* a = agg + (size_t)nid * 32;
  float av[32];
#pragma unroll
  for (int o = 0; o < 32; o += 4) {
    uint4 u = *(const uint4*)(a + o);
    av[o] = __uint_as_float(u.x);
    av[o + 1] = __uint_as_float(u.y);
    av[o + 2] = __uint_as_float(u.z);
    av[o + 3] = __uint_as_float(u.w);
    *(uint4*)(a + o) = make_uint4(0u, 0u, 0u, 0u);
  }
  float4 xs = x4in[nid];
  float h[16];
#pragma unroll
  for (int o = 0; o < 16; o++) {
    float sa = wg[1200 + o];  // b3
    sa = fmaf(wg[640 + o * 35 + 0], xs.x, sa);
    sa = fmaf(wg[640 + o * 35 + 1], xs.y, sa);
    sa = fmaf(wg[640 + o * 35 + 2], xs.z, sa);
#pragma unroll
    for (int k = 0; k < 32; k++) sa = fmaf(wg[640 + o * 35 + 3 + k], av[k], sa);
    h[o] = fmaxf(sa, 0.f);
  }
  float z = wg[1232];  // b4
#pragma unroll
  for (int k = 0; k < 16; k++) z = fmaf(wg[1216 + k], h[k], z);
  float comb = 1.f / (1.f + expf(-z));
  x4out[nid] = make_float4(xs.x, xs.y, comb, 0.f);
  if (outFinal) {
    outFinal[3 * nid] = xs.x;
    outFinal[3 * nid + 1] = xs.y;
    outFinal[3 * nid + 2] = comb;
  }
}

extern "C" void kernel_launch(void* const* d_in, const int* in_sizes, int n_in,
                              void* d_out, int out_size, void* d_ws, size_t ws_size,
                              hipStream_t stream) {
  const float* x = (const float*)d_in[0];
  const float* ea = (const float*)d_in[1];
  const int* eidx = (const int*)d_in[2];
  const int N = in_sizes[0] / 3;
  const int E = in_sizes[1] / 2;
  const int* src = eidx;
  const int* dst = eidx + E;

  // ---- workspace carve-up ----
  char* p = (char*)d_ws;
  size_t off = 0;
  auto alloc = [&](size_t bytes) -> char* {
    char* r = p + off;
    off = (off + bytes + 255) & ~(size_t)255;
    return r;
  };
  float* wbuf = (float*)alloc((size_t)WTOT * 4);
  int* deg = (int*)alloc((size_t)N * 4);
  int* row = (int*)alloc(((size_t)N + 1) * 4);
  int* cursor = (int*)alloc((size_t)N * 4);
  int4* erec = (int4*)alloc((size_t)E * 16);
  unsigned int* agg = (unsigned int*)alloc((size_t)N * 32 * 4);
  float4* x4a = (float4*)alloc((size_t)N * 16);
  float4* x4b = (float4*)alloc((size_t)N * 16);
  (void)ws_size;

  PrepArgs pa;
  for (int l = 0; l < 4; l++) {
    pa.wmu[l] = (const float*)d_in[3 + 6 * l + 0];
    pa.wrho[l] = (const float*)d_in[3 + 6 * l + 1];
    pa.bmu[l] = (const float*)d_in[3 + 6 * l + 2];
    pa.brho[l] = (const float*)d_in[3 + 6 * l + 3];
    pa.epsw[l] = (const float*)d_in[3 + 6 * l + 4];
    pa.epsb[l] = (const float*)d_in[3 + 6 * l + 5];
  }
  pa.out = wbuf;

  const int TB = 256;
  auto blocks = [&](int n) { return dim3((n + TB - 1) / TB); };

  zero_kernel<<<blocks(N), dim3(TB), 0, stream>>>(deg, N);
  prep_kernel<<<dim3(8), dim3(128), 0, stream>>>(pa);
  count_kernel<<<blocks(E), dim3(TB), 0, stream>>>(dst, deg, E);
  scan_kernel<<<dim3(1), dim3(1024), 0, stream>>>(deg, row, cursor, N);
  fill_kernel<<<blocks(E), dim3(TB), 0, stream>>>(src, dst, (const float2*)ea, cursor,
                                                  erec, E);
  xprep_kernel<<<blocks(N), dim3(TB), 0, stream>>>(x, x4a, N);
  int n4 = N * 8;  // N*32 uints as uint4
  zero4_kernel<<<blocks(n4), dim3(TB), 0, stream>>>((uint4*)agg, n4);

  float* outp = (float*)d_out;
  // iter 1
  edge_kernel<<<blocks(E), dim3(TB), 0, stream>>>(x4a, erec, agg, wbuf, E);
  node_kernel<<<blocks(N), dim3(TB), 0, stream>>>(x4a, x4b, nullptr, agg, wbuf, N);
  // iter 2
  edge_kernel<<<blocks(E), dim3(TB), 0, stream>>>(x4b, erec, agg, wbuf, E);
  node_kernel<<<blocks(N), dim3(TB), 0, stream>>>(x4b, x4a, nullptr, agg, wbuf, N);
  // iter 3
  edge_kernel<<<blocks(E), dim3(TB), 0, stream>>>(x4a, erec, agg, wbuf, E);
  node_kernel<<<blocks(N), dim3(TB), 0, stream>>>(x4a, x4b, outp, agg, wbuf, N);
}